// Round 1
// baseline (746.467 us; speedup 1.0000x reference)
//
#include <hip/hip_runtime.h>
#include <hip/hip_bf16.h>
#include <stdint.h>

typedef unsigned short u16;
typedef __attribute__((ext_vector_type(8))) short frag8;   // 8 bf16 (4 VGPRs)
typedef __attribute__((ext_vector_type(4))) float f4;      // 4 f32 acc

#define N8K 8192
#define SK 8   // split-K slices for big GEMM

__device__ __forceinline__ u16 f2bf(float f) {
  union { float f; unsigned u; } v; v.f = f;
  return (u16)((v.u + 0x7FFFu + ((v.u >> 16) & 1u)) >> 16);   // RNE
}
__device__ __forceinline__ float lrelu(float v) { return v > 0.f ? v : 0.01f * v; }

__device__ __forceinline__ void gld16(const void* g, void* l) {
  __builtin_amdgcn_global_load_lds(
      (__attribute__((address_space(1))) unsigned*)(g),
      (__attribute__((address_space(3))) unsigned*)(l), 16, 0, 0);
}

// ---------------- deg + A_hat(bf16) + dinv ----------------
// one block per row; reads int32 row (32KB), writes bf16 row (16KB), reduces degree
__global__ __launch_bounds__(256) void k_deg(const int* __restrict__ e,
                                             u16* __restrict__ abf,
                                             float* __restrict__ dinv) {
  int row = blockIdx.x;
  int t = threadIdx.x;
  const int4* er = (const int4*)(e + (size_t)row * N8K);
  ushort4* ar = (ushort4*)(abf + (size_t)row * N8K);
  int cnt = 0;
#pragma unroll
  for (int it = 0; it < 8; ++it) {
    int j4 = it * 256 + t;
    int4 v = er[j4];
    int col = j4 << 2;
    int c0 = (v.x != 0), c1 = (v.y != 0), c2 = (v.z != 0), c3 = (v.w != 0);
    cnt += c0 + c1 + c2 + c3;
    ushort4 a;
    a.x = c0 ? 0x3F80u : 0u;
    a.y = c1 ? 0x3F80u : 0u;
    a.z = c2 ? 0x3F80u : 0u;
    a.w = c3 ? 0x3F80u : 0u;
    if (row >= col && row < col + 4) {          // self-loop: A_hat[i][i] = A[i][i] + 1
      u16* ap = (u16*)&a;
      int d = row - col;
      ap[d] = ap[d] ? 0x4000u : 0x3F80u;        // 1->2, 0->1 (exact in bf16)
      cnt += 1;
    }
    ar[j4] = a;
  }
#pragma unroll
  for (int o = 32; o > 0; o >>= 1) cnt += __shfl_down(cnt, o);
  __shared__ int part[4];
  if ((t & 63) == 0) part[t >> 6] = cnt;
  __syncthreads();
  if (t == 0) dinv[row] = 1.0f / sqrtf((float)(part[0] + part[1] + part[2] + part[3]));
}

// ---------------- f32 -> bf16 convert ----------------
__global__ __launch_bounds__(256) void k_cvt(const float* __restrict__ x, u16* __restrict__ xb, int n) {
  int i = blockIdx.x * 256 + threadIdx.x;
  if (i < n) xb[i] = f2bf(x[i]);
}

// ---------------- small GEMM: P_t[c][i] = dinv[i] * (X[i][:] . W[:][c]) ----------------
// X: [8192][kc] bf16. W built into LDS transposed [n=128][k=kc] from f32 inputs
// (Wa with wacols columns; optional Wb supplying columns 64..127; pad with 0).
// grid 64 blocks x 256 threads; 128x128 C-tile per block, 4 waves in 2x2.
__global__ __launch_bounds__(256) void k_sgemm(const u16* __restrict__ X, int kc, int lkc,
                                               const float* __restrict__ Wa, int wacols,
                                               const float* __restrict__ Wb,
                                               const float* __restrict__ dinv,
                                               u16* __restrict__ Pt) {
  __shared__ __attribute__((aligned(16))) u16 Xs[128 * 128];
  __shared__ __attribute__((aligned(16))) u16 Wt[128 * 128];
  int t = threadIdx.x;
  int mt = blockIdx.x;
  for (int idx = t; idx < (kc << 7); idx += 256) {
    int n = idx >> lkc, k = idx & (kc - 1);
    float v = 0.f;
    if (n < wacols) v = Wa[k * wacols + n];
    else if (Wb)    v = Wb[k * 64 + (n - 64)];
    Wt[(n << lkc) + k] = f2bf(v);
  }
  const u16* gX = X + (size_t)mt * 128 * kc;
  if (kc == 128) {
#pragma unroll
    for (int p = 0; p < 8; ++p) {
      int rr = p * 16 + (t >> 4), sg = t & 15;
      gld16(gX + rr * 128 + sg * 8, Xs + rr * 128 + sg * 8);
    }
  } else {
#pragma unroll
    for (int p = 0; p < 4; ++p) {
      int rr = p * 32 + (t >> 3), sg = t & 7;
      gld16(gX + rr * 64 + sg * 8, Xs + rr * 64 + sg * 8);
    }
  }
  __syncthreads();
  int wave = t >> 6, lane = t & 63;
  int wm = (wave >> 1) * 64, wn = (wave & 1) * 64;
  int fm = lane & 15, fk = (lane >> 4) * 8;
  f4 acc[4][4];
#pragma unroll
  for (int m = 0; m < 4; ++m)
#pragma unroll
    for (int n = 0; n < 4; ++n) acc[m][n] = (f4){0.f, 0.f, 0.f, 0.f};
  for (int ki = 0; ki < kc; ki += 32) {
    frag8 a[4], b[4];
#pragma unroll
    for (int m = 0; m < 4; ++m) a[m] = *(const frag8*)&Xs[(wm + 16 * m + fm) * kc + ki + fk];
#pragma unroll
    for (int n = 0; n < 4; ++n) b[n] = *(const frag8*)&Wt[((wn + 16 * n + fm) << lkc) + ki + fk];
#pragma unroll
    for (int m = 0; m < 4; ++m)
#pragma unroll
      for (int n = 0; n < 4; ++n)
        acc[m][n] = __builtin_amdgcn_mfma_f32_16x16x32_bf16(a[m], b[n], acc[m][n], 0, 0, 0);
  }
  int rbase = (lane >> 4) * 4;
#pragma unroll
  for (int m = 0; m < 4; ++m) {
    int i0 = mt * 128 + wm + 16 * m + rbase;
    float d0 = dinv[i0], d1 = dinv[i0 + 1], d2 = dinv[i0 + 2], d3 = dinv[i0 + 3];
#pragma unroll
    for (int n = 0; n < 4; ++n) {
      int c = wn + 16 * n + fm;
      ushort4 o;
      o.x = f2bf(d0 * acc[m][n][0]);
      o.y = f2bf(d1 * acc[m][n][1]);
      o.z = f2bf(d2 * acc[m][n][2]);
      o.w = f2bf(d3 * acc[m][n][3]);
      *(ushort4*)&Pt[(size_t)c * N8K + i0] = o;   // P stored transposed [c][i]
    }
  }
}

// ---------------- big GEMM (split-K): Ctmp[ks] += A_hat @ P ----------------
// A: [8192][8192] bf16 row-major; Pt: [128][8192] bf16 (n-major => B^T rows).
// grid (64, SK) x 256 threads; 128x128 tile, BK=64, m97-style global_load_lds staging.
__global__ __launch_bounds__(256) void k_bgemm(const u16* __restrict__ A,
                                               const u16* __restrict__ Pt,
                                               float* __restrict__ Ctmp) {
  __shared__ __attribute__((aligned(16))) u16 As[128 * 64];
  __shared__ __attribute__((aligned(16))) u16 Bs[128 * 64];
  int t = threadIdx.x;
  int mt = blockIdx.x, ks = blockIdx.y;
  const int KS = N8K / SK;
  int wave = t >> 6, lane = t & 63;
  int wm = (wave >> 1) * 64, wn = (wave & 1) * 64;
  int fm = lane & 15, fk = (lane >> 4) * 8;
  f4 acc[4][4];
#pragma unroll
  for (int m = 0; m < 4; ++m)
#pragma unroll
    for (int n = 0; n < 4; ++n) acc[m][n] = (f4){0.f, 0.f, 0.f, 0.f};

  int arow = t >> 3, aseg = t & 7;
  const u16* gA0 = A + (size_t)(mt * 128 + arow) * N8K + aseg * 8;
  const u16* gB0 = Pt + (size_t)arow * N8K + aseg * 8;
  u16* lA = As + arow * 64 + aseg * 8;
  u16* lB = Bs + arow * 64 + aseg * 8;

  for (int kk = ks * KS; kk < ks * KS + KS; kk += 64) {
    __syncthreads();
#pragma unroll
    for (int p = 0; p < 4; ++p) {
      gld16(gA0 + (size_t)p * 32 * N8K + kk, lA + p * 32 * 64);
      gld16(gB0 + (size_t)p * 32 * N8K + kk, lB + p * 32 * 64);
    }
    __syncthreads();
#pragma unroll
    for (int ki = 0; ki < 64; ki += 32) {
      frag8 a[4], b[4];
#pragma unroll
      for (int m = 0; m < 4; ++m) a[m] = *(const frag8*)&As[(wm + 16 * m + fm) * 64 + ki + fk];
#pragma unroll
      for (int n = 0; n < 4; ++n) b[n] = *(const frag8*)&Bs[(wn + 16 * n + fm) * 64 + ki + fk];
#pragma unroll
      for (int m = 0; m < 4; ++m)
#pragma unroll
        for (int n = 0; n < 4; ++n)
          acc[m][n] = __builtin_amdgcn_mfma_f32_16x16x32_bf16(a[m], b[n], acc[m][n], 0, 0, 0);
    }
  }
  float* Co = Ctmp + (size_t)ks * N8K * 128;
  int rbase = (lane >> 4) * 4;
#pragma unroll
  for (int m = 0; m < 4; ++m) {
    int i0 = mt * 128 + wm + 16 * m + rbase;
#pragma unroll
    for (int n = 0; n < 4; ++n) {
      int c = wn + 16 * n + fm;
#pragma unroll
      for (int r = 0; r < 4; ++r) Co[(size_t)(i0 + r) * 128 + c] = acc[m][n][r];
    }
  }
}

// ---------------- epilogue: sum split-K, scale by dinv, +bias, lrelu, scatter ----------------
// mode 1: h_bf (c<64, bias bA)      mode 2: z f32 + z_bf (bias bA)
// mode 3: re_bf(c<64,bA) / xd_bf(c>=64,bB)   mode 4: x_out f32 (bias bA)
__global__ __launch_bounds__(256) void k_epi(const float* __restrict__ Ctmp, const float* __restrict__ dinv,
                                             const float* __restrict__ bA, const float* __restrict__ bB,
                                             float* __restrict__ outF, u16* __restrict__ oB1,
                                             u16* __restrict__ oB2, int mode) {
  int idx = blockIdx.x * 256 + threadIdx.x;
  int i = idx >> 7, c = idx & 127;
  float s = 0.f;
#pragma unroll
  for (int k = 0; k < SK; ++k) s += Ctmp[(size_t)k * 1048576 + idx];
  if (mode == 1) {
    if (c < 64) oB1[i * 64 + c] = f2bf(lrelu(dinv[i] * s + bA[c]));
  } else if (mode == 2) {
    float v = lrelu(dinv[i] * s + bA[c]);
    outF[idx] = v;
    oB1[idx] = f2bf(v);
  } else if (mode == 3) {
    if (c < 64) oB1[i * 64 + c] = f2bf(lrelu(dinv[i] * s + bA[c]));
    else        oB2[i * 64 + (c - 64)] = f2bf(lrelu(dinv[i] * s + bB[c - 64]));
  } else {
    outF[idx] = lrelu(dinv[i] * s + bA[c]);
  }
}

// ---------------- recon = sigmoid(re @ re^T) ----------------
// grid (64,64) x 256; 128x128 tile, K=64; re rows serve as both A and B^T rows.
__global__ __launch_bounds__(256) void k_recon(const u16* __restrict__ re, float* __restrict__ out) {
  __shared__ __attribute__((aligned(16))) u16 Ra[128 * 64];
  __shared__ __attribute__((aligned(16))) u16 Rb[128 * 64];
  int t = threadIdx.x;
  int bi = blockIdx.x, bj = blockIdx.y;
  int r0 = t >> 3, sg = t & 7;
#pragma unroll
  for (int p = 0; p < 4; ++p) {
    int rr = p * 32 + r0;
    gld16(re + (size_t)(bi * 128 + rr) * 64 + sg * 8, Ra + rr * 64 + sg * 8);
    gld16(re + (size_t)(bj * 128 + rr) * 64 + sg * 8, Rb + rr * 64 + sg * 8);
  }
  __syncthreads();
  int wave = t >> 6, lane = t & 63;
  int wm = (wave >> 1) * 64, wn = (wave & 1) * 64;
  int fm = lane & 15, fk = (lane >> 4) * 8;
  f4 acc[4][4];
#pragma unroll
  for (int m = 0; m < 4; ++m)
#pragma unroll
    for (int n = 0; n < 4; ++n) acc[m][n] = (f4){0.f, 0.f, 0.f, 0.f};
#pragma unroll
  for (int ki = 0; ki < 64; ki += 32) {
    frag8 a[4], b[4];
#pragma unroll
    for (int m = 0; m < 4; ++m) a[m] = *(const frag8*)&Ra[(wm + 16 * m + fm) * 64 + ki + fk];
#pragma unroll
    for (int n = 0; n < 4; ++n) b[n] = *(const frag8*)&Rb[(wn + 16 * n + fm) * 64 + ki + fk];
#pragma unroll
    for (int m = 0; m < 4; ++m)
#pragma unroll
      for (int n = 0; n < 4; ++n)
        acc[m][n] = __builtin_amdgcn_mfma_f32_16x16x32_bf16(a[m], b[n], acc[m][n], 0, 0, 0);
  }
  int rbase = (lane >> 4) * 4;
#pragma unroll
  for (int m = 0; m < 4; ++m) {
#pragma unroll
    for (int n = 0; n < 4; ++n) {
      int gj = bj * 128 + wn + 16 * n + fm;
#pragma unroll
      for (int r = 0; r < 4; ++r) {
        int gi = bi * 128 + wm + 16 * m + rbase + r;
        float v = acc[m][n][r];
        out[(size_t)gi * N8K + gj] = 1.0f / (1.0f + __expf(-v));
      }
    }
  }
}

extern "C" void kernel_launch(void* const* d_in, const int* in_sizes, int n_in,
                              void* d_out, int out_size, void* d_ws, size_t ws_size,
                              hipStream_t stream) {
  const float* x   = (const float*)d_in[0];
  const int*   e   = (const int*)d_in[1];
  const float* W1  = (const float*)d_in[2];
  const float* b1  = (const float*)d_in[3];
  const float* W2  = (const float*)d_in[4];
  const float* b2  = (const float*)d_in[5];
  const float* We  = (const float*)d_in[6];
  const float* be  = (const float*)d_in[7];
  const float* Wd1 = (const float*)d_in[8];
  const float* bd1 = (const float*)d_in[9];
  const float* Wd2 = (const float*)d_in[10];
  const float* bd2 = (const float*)d_in[11];

  float* out       = (float*)d_out;
  float* out_recon = out;                         // [8192*8192]
  float* out_x     = out + 67108864;              // [8192*128]
  float* out_z     = out + 67108864 + 1048576;    // [8192*128]

  // Big scratch aliased into the recon region of d_out (overwritten only by k_recon at the end):
  u16*   abf  = (u16*)d_out;                      // A_hat bf16: 128 MB (first half of recon region)
  float* Ctmp = out + 33554432;                   // split-K partials: 32 MB (second half)

  char* ws = (char*)d_ws;                         // ~9 MB of d_ws used
  float* dinv = (float*)(ws);
  u16* Pt   = (u16*)(ws + 32768);
  u16* xbf  = (u16*)(ws + 32768 + 2097152);
  u16* hbf  = (u16*)(ws + 32768 + 2097152 + 2097152);
  u16* zbf  = (u16*)(ws + 32768 + 2097152 + 2097152 + 1048576);
  u16* rebf = (u16*)(ws + 32768 + 2097152 + 2097152 + 1048576 + 2097152);
  u16* xdbf = (u16*)(ws + 32768 + 2097152 + 2097152 + 1048576 + 2097152 + 1048576);

  k_deg<<<8192, 256, 0, stream>>>(e, abf, dinv);
  k_cvt<<<4096, 256, 0, stream>>>(x, xbf, 1048576);

  // stage 1: h = lrelu(dinv * (A_hat @ (dinv*(x@W1))) + b1)   (cols 64..127 zero-padded)
  k_sgemm<<<64, 256, 0, stream>>>(xbf, 128, 7, W1, 64, nullptr, dinv, Pt);
  k_bgemm<<<dim3(64, SK), 256, 0, stream>>>(abf, Pt, Ctmp);
  k_epi<<<4096, 256, 0, stream>>>(Ctmp, dinv, b1, nullptr, nullptr, hbf, nullptr, 1);

  // stage 2: z
  k_sgemm<<<64, 256, 0, stream>>>(hbf, 64, 6, W2, 128, nullptr, dinv, Pt);
  k_bgemm<<<dim3(64, SK), 256, 0, stream>>>(abf, Pt, Ctmp);
  k_epi<<<4096, 256, 0, stream>>>(Ctmp, dinv, b2, nullptr, out_z, zbf, nullptr, 2);

  // stage 3: [re | xd] in one GEMM via [We | Wd1]
  k_sgemm<<<64, 256, 0, stream>>>(zbf, 128, 7, We, 64, Wd1, dinv, Pt);
  k_bgemm<<<dim3(64, SK), 256, 0, stream>>>(abf, Pt, Ctmp);
  k_epi<<<4096, 256, 0, stream>>>(Ctmp, dinv, be, bd1, nullptr, rebf, xdbf, 3);

  // stage 4: x_out
  k_sgemm<<<64, 256, 0, stream>>>(xdbf, 64, 6, Wd2, 128, nullptr, dinv, Pt);
  k_bgemm<<<dim3(64, SK), 256, 0, stream>>>(abf, Pt, Ctmp);
  k_epi<<<4096, 256, 0, stream>>>(Ctmp, dinv, bd2, nullptr, out_x, nullptr, nullptr, 4);

  // recon = sigmoid(re @ re^T)  — overwrites the abf/Ctmp scratch region last
  k_recon<<<dim3(64, 64), 256, 0, stream>>>(rebf, out_recon);
}